// Round 4
// baseline (170.787 us; speedup 1.0000x reference)
//
#include <hip/hip_runtime.h>
#include <hip/hip_cooperative_groups.h>

namespace cg = cooperative_groups;

#define SEQ 65536
#define HID 1024
#define BLOCKS 1024
#define WPB 4                      // waves per block
#define NW (BLOCKS * WPB)          // 4096 waves
#define RPW (SEQ / NW)             // 16 rows per wave, contiguous chunk
#define CHUNK (SEQ / BLOCKS)       // 64 outputs per block in phase 2

typedef float f4 __attribute__((ext_vector_type(4)));

// Fused: matvec + per-block softmax stats -> grid sync -> global stats
// reduce + normalize. One dispatch, no atomics, no ws init needed.
__global__ __launch_bounds__(256, 4) void k_fused(
        const float* __restrict__ enc,
        const float* __restrict__ hid,
        float* __restrict__ out,
        float2* __restrict__ stats) {     // ws[0..BLOCKS)
    const int lane = threadIdx.x & 63;
    const int wid  = threadIdx.x >> 6;
    const int gw   = blockIdx.x * WPB + wid;
    const size_t base = (size_t)gw * RPW;

    // hidden hoisted into 16 regs/lane (row-invariant, L2-resident)
    const f4* __restrict__ h4 = (const f4*)hid;
    const f4 h0 = h4[lane];
    const f4 h1 = h4[lane + 64];
    const f4 h2 = h4[lane + 128];
    const f4 h3 = h4[lane + 192];

    // ---- phase 1: energies + per-wave online (max, sum_exp) ----
    float wmax = -INFINITY, wsum = 0.0f;
    #pragma unroll 4
    for (int r = 0; r < RPW; ++r) {
        const f4* __restrict__ row = (const f4*)(enc + (base + r) * HID);
        f4 a0 = __builtin_nontemporal_load(row + lane);
        f4 a1 = __builtin_nontemporal_load(row + lane + 64);
        f4 a2 = __builtin_nontemporal_load(row + lane + 128);
        f4 a3 = __builtin_nontemporal_load(row + lane + 192);
        float s = a0.x*h0.x + a0.y*h0.y + a0.z*h0.z + a0.w*h0.w
                + a1.x*h1.x + a1.y*h1.y + a1.z*h1.z + a1.w*h1.w
                + a2.x*h2.x + a2.y*h2.y + a2.z*h2.z + a2.w*h2.w
                + a3.x*h3.x + a3.y*h3.y + a3.z*h3.z + a3.w*h3.w;
        #pragma unroll
        for (int off = 32; off >= 1; off >>= 1)
            s += __shfl_xor(s, off, 64);
        if (lane == 0) out[base + r] = s;      // scratch (re-read in phase 2)
        float nm = fmaxf(wmax, s);             // all lanes hold identical s
        wsum = wsum * __expf(wmax - nm) + __expf(s - nm);
        wmax = nm;
    }

    __shared__ float sm[WPB], ss[WPB];
    if (lane == 0) { sm[wid] = wmax; ss[wid] = wsum; }
    __syncthreads();
    if (threadIdx.x == 0) {
        float m = fmaxf(fmaxf(sm[0], sm[1]), fmaxf(sm[2], sm[3]));
        float s = ss[0]*__expf(sm[0]-m) + ss[1]*__expf(sm[1]-m)
                + ss[2]*__expf(sm[2]-m) + ss[3]*__expf(sm[3]-m);
        stats[blockIdx.x] = make_float2(m, s);
    }

    cg::this_grid().sync();   // device-scope fence + grid barrier

    // ---- phase 2: every block reduces all 1024 stats (8 KiB, cached) ----
    float m = -INFINITY, s = 0.0f;
    #pragma unroll
    for (int k = 0; k < BLOCKS / 256; ++k) {
        float2 st = stats[k * 256 + threadIdx.x];
        float nm = fmaxf(m, st.x);
        s = s * __expf(m - nm) + st.y * __expf(st.x - nm);
        m = nm;
    }
    #pragma unroll
    for (int off = 32; off >= 1; off >>= 1) {
        float om = __shfl_xor(m, off, 64);
        float os = __shfl_xor(s, off, 64);
        float nm = fmaxf(m, om);
        s = s * __expf(m - nm) + os * __expf(om - nm);
        m = nm;
    }
    __shared__ float sm2[WPB], ss2[WPB];
    if (lane == 0) { sm2[wid] = m; ss2[wid] = s; }
    __syncthreads();
    const float M = fmaxf(fmaxf(sm2[0], sm2[1]), fmaxf(sm2[2], sm2[3]));
    const float S = ss2[0]*__expf(sm2[0]-M) + ss2[1]*__expf(sm2[1]-M)
                  + ss2[2]*__expf(sm2[2]-M) + ss2[3]*__expf(sm2[3]-M);
    const float invS = 1.0f / S;

    // normalize exactly the chunk this block computed (L2-local)
    if (threadIdx.x < CHUNK / 4) {
        const int i = blockIdx.x * CHUNK + threadIdx.x * 4;
        float4 e = *(const float4*)(out + i);
        e.x = __expf(e.x - M) * invS;
        e.y = __expf(e.y - M) * invS;
        e.z = __expf(e.z - M) * invS;
        e.w = __expf(e.w - M) * invS;
        *(float4*)(out + i) = e;
    }
}

extern "C" void kernel_launch(void* const* d_in, const int* in_sizes, int n_in,
                              void* d_out, int out_size, void* d_ws, size_t ws_size,
                              hipStream_t stream) {
    const float* hid = (const float*)d_in[0];   // hidden   [1024]
    const float* enc = (const float*)d_in[1];   // encoder  [65536,1024]
    float* out = (float*)d_out;                 // [65536]
    float2* stats = (float2*)d_ws;              // 1024 * 8 B = 8 KiB

    void* args[] = { (void*)&enc, (void*)&hid, (void*)&out, (void*)&stats };
    hipLaunchCooperativeKernel((const void*)k_fused,
                               dim3(BLOCKS), dim3(256), args, 0, stream);
}

// Round 5
// 50.011 us; speedup vs baseline: 3.4150x; 3.4150x over previous
//
#include <hip/hip_runtime.h>

#define SEQ 65536
#define HID 1024
#define K1_BLOCKS 2048
#define WPB 4                       // waves per block
#define NWAVES (K1_BLOCKS * WPB)    // 8192
#define RPW (SEQ / NWAVES)          // 8 rows per wave, contiguous chunk

typedef float f4 __attribute__((ext_vector_type(4)));

// K1: energies[r] = enc[r,:] . hid (one wave per row), register-double-
// buffered row prefetch for MLP depth, per-block softmax stats to ws.
__global__ __launch_bounds__(256) void k_matvec_stats(
        const float* __restrict__ enc,
        const float* __restrict__ hid,
        float* __restrict__ energies,      // d_out reused as scratch
        float2* __restrict__ stats) {      // ws[0..2047]
    const int lane = threadIdx.x & 63;
    const int wid  = threadIdx.x >> 6;
    const int gw   = blockIdx.x * WPB + wid;
    const size_t base = (size_t)gw * RPW;

    // hidden hoisted into 16 regs/lane (row-invariant, L1/L2-resident)
    const f4* __restrict__ h4 = (const f4*)hid;
    const f4 h0 = h4[lane];
    const f4 h1 = h4[lane + 64];
    const f4 h2 = h4[lane + 128];
    const f4 h3 = h4[lane + 192];

    const f4* __restrict__ rowp = (const f4*)(enc + base * HID) + lane;

    // prime the pipeline: row 0 in flight
    f4 a0 = __builtin_nontemporal_load(rowp);
    f4 a1 = __builtin_nontemporal_load(rowp + 64);
    f4 a2 = __builtin_nontemporal_load(rowp + 128);
    f4 a3 = __builtin_nontemporal_load(rowp + 192);

    float wmax = -INFINITY, wsum = 0.0f;
    #pragma unroll
    for (int r = 0; r < RPW; ++r) {
        f4 b0, b1, b2, b3;
        if (r + 1 < RPW) {                 // compile-time guard (full unroll)
            const f4* nxt = rowp + (size_t)(r + 1) * (HID / 4);
            b0 = __builtin_nontemporal_load(nxt);
            b1 = __builtin_nontemporal_load(nxt + 64);
            b2 = __builtin_nontemporal_load(nxt + 128);
            b3 = __builtin_nontemporal_load(nxt + 192);
        }
        float s = a0.x*h0.x + a0.y*h0.y + a0.z*h0.z + a0.w*h0.w
                + a1.x*h1.x + a1.y*h1.y + a1.z*h1.z + a1.w*h1.w
                + a2.x*h2.x + a2.y*h2.y + a2.z*h2.z + a2.w*h2.w
                + a3.x*h3.x + a3.y*h3.y + a3.z*h3.z + a3.w*h3.w;
        #pragma unroll
        for (int off = 32; off >= 1; off >>= 1)
            s += __shfl_xor(s, off, 64);
        if (lane == 0) energies[base + r] = s;
        // online max/sum (all lanes hold identical s)
        float nm = fmaxf(wmax, s);
        wsum = wsum * __expf(wmax - nm) + __expf(s - nm);
        wmax = nm;
        if (r + 1 < RPW) { a0 = b0; a1 = b1; a2 = b2; a3 = b3; }
    }

    __shared__ float sm[WPB], ss[WPB];
    if (lane == 0) { sm[wid] = wmax; ss[wid] = wsum; }
    __syncthreads();
    if (threadIdx.x == 0) {
        float m = fmaxf(fmaxf(sm[0], sm[1]), fmaxf(sm[2], sm[3]));
        float s = ss[0]*__expf(sm[0]-m) + ss[1]*__expf(sm[1]-m)
                + ss[2]*__expf(sm[2]-m) + ss[3]*__expf(sm[3]-m);
        stats[blockIdx.x] = make_float2(m, s);
    }
}

// K2: every block redundantly reduces the 2048 (max,sum) stats (16 KiB,
// L2-hit), then exp+normalizes its 1024-element chunk in one pass.
__global__ __launch_bounds__(256) void k_softmax_scale(
        float* __restrict__ out,
        const float2* __restrict__ stats) {
    float m = -INFINITY, s = 0.0f;
    #pragma unroll
    for (int k = 0; k < K1_BLOCKS / 256; ++k) {
        float2 st = stats[k * 256 + threadIdx.x];
        float nm = fmaxf(m, st.x);
        s = s * __expf(m - nm) + st.y * __expf(st.x - nm);
        m = nm;
    }
    #pragma unroll
    for (int off = 32; off >= 1; off >>= 1) {
        float om = __shfl_xor(m, off, 64);
        float os = __shfl_xor(s, off, 64);
        float nm = fmaxf(m, om);
        s = s * __expf(m - nm) + os * __expf(om - nm);
        m = nm;
    }
    __shared__ float sm[4], ss[4];
    const int lane = threadIdx.x & 63, wid = threadIdx.x >> 6;
    if (lane == 0) { sm[wid] = m; ss[wid] = s; }
    __syncthreads();
    const float M = fmaxf(fmaxf(sm[0], sm[1]), fmaxf(sm[2], sm[3]));
    const float S = ss[0]*__expf(sm[0]-M) + ss[1]*__expf(sm[1]-M)
                  + ss[2]*__expf(sm[2]-M) + ss[3]*__expf(sm[3]-M);
    const float invS = 1.0f / S;

    const int i = (blockIdx.x * 256 + threadIdx.x) * 4;
    float4 e = *(const float4*)(out + i);
    e.x = __expf(e.x - M) * invS;
    e.y = __expf(e.y - M) * invS;
    e.z = __expf(e.z - M) * invS;
    e.w = __expf(e.w - M) * invS;
    *(float4*)(out + i) = e;
}

extern "C" void kernel_launch(void* const* d_in, const int* in_sizes, int n_in,
                              void* d_out, int out_size, void* d_ws, size_t ws_size,
                              hipStream_t stream) {
    const float* hid = (const float*)d_in[0];   // hidden   [1024]
    const float* enc = (const float*)d_in[1];   // encoder  [65536,1024]
    float* out = (float*)d_out;                 // [65536]
    float2* stats = (float2*)d_ws;              // 2048 * 8 B = 16 KiB

    k_matvec_stats  <<<K1_BLOCKS, 256, 0, stream>>>(enc, hid, out, stats);
    k_softmax_scale <<<SEQ / (256 * 4), 256, 0, stream>>>(out, stats);
}

// Round 6
// 48.506 us; speedup vs baseline: 3.5209x; 1.0310x over previous
//
#include <hip/hip_runtime.h>
#include <hip/hip_cooperative_groups.h>

namespace cg = cooperative_groups;

#define SEQ 65536
#define HID 1024
#define BLOCKS 2048
#define WPB 4                       // waves per block
#define NWAVES (BLOCKS * WPB)       // 8192
#define RPW (SEQ / NWAVES)          // 8 rows per wave
#define CHUNK (SEQ / BLOCKS)        // 32 outputs per block (coop phase 2)

typedef float f4 __attribute__((ext_vector_type(4)));

// ---- phase 1 (exact R3 body): matvec + per-block (max, sum_exp) ----
__device__ __forceinline__ void phase1(
        const float* __restrict__ enc, const float* __restrict__ hid,
        float* __restrict__ energies, float2* __restrict__ stats) {
    const int lane = threadIdx.x & 63;
    const int wid  = threadIdx.x >> 6;
    const int gw   = blockIdx.x * WPB + wid;
    const size_t base = (size_t)gw * RPW;

    const f4* __restrict__ h4 = (const f4*)hid;
    const f4 h0 = h4[lane];
    const f4 h1 = h4[lane + 64];
    const f4 h2 = h4[lane + 128];
    const f4 h3 = h4[lane + 192];

    float wmax = -INFINITY, wsum = 0.0f;
    #pragma unroll
    for (int r = 0; r < RPW; ++r) {
        const f4* __restrict__ row = (const f4*)(enc + (base + r) * HID);
        f4 a0 = __builtin_nontemporal_load(row + lane);
        f4 a1 = __builtin_nontemporal_load(row + lane + 64);
        f4 a2 = __builtin_nontemporal_load(row + lane + 128);
        f4 a3 = __builtin_nontemporal_load(row + lane + 192);
        float s = a0.x*h0.x + a0.y*h0.y + a0.z*h0.z + a0.w*h0.w
                + a1.x*h1.x + a1.y*h1.y + a1.z*h1.z + a1.w*h1.w
                + a2.x*h2.x + a2.y*h2.y + a2.z*h2.z + a2.w*h2.w
                + a3.x*h3.x + a3.y*h3.y + a3.z*h3.z + a3.w*h3.w;
        #pragma unroll
        for (int off = 32; off >= 1; off >>= 1)
            s += __shfl_xor(s, off, 64);
        if (lane == 0) energies[base + r] = s;
        float nm = fmaxf(wmax, s);              // all lanes hold identical s
        wsum = wsum * __expf(wmax - nm) + __expf(s - nm);
        wmax = nm;
    }

    __shared__ float sm[WPB], ss[WPB];
    if (lane == 0) { sm[wid] = wmax; ss[wid] = wsum; }
    __syncthreads();
    if (threadIdx.x == 0) {
        float m = fmaxf(fmaxf(sm[0], sm[1]), fmaxf(sm[2], sm[3]));
        float s = ss[0]*__expf(sm[0]-m) + ss[1]*__expf(sm[1]-m)
                + ss[2]*__expf(sm[2]-m) + ss[3]*__expf(sm[3]-m);
        stats[blockIdx.x] = make_float2(m, s);
    }
}

// ---- redundant per-block reduce of all BLOCKS stats -> (M, 1/S) ----
__device__ __forceinline__ float2 reduce_stats(const float2* __restrict__ stats) {
    float m = -INFINITY, s = 0.0f;
    #pragma unroll
    for (int k = 0; k < BLOCKS / 256; ++k) {
        float2 st = stats[k * 256 + threadIdx.x];
        float nm = fmaxf(m, st.x);
        s = s * __expf(m - nm) + st.y * __expf(st.x - nm);
        m = nm;
    }
    #pragma unroll
    for (int off = 32; off >= 1; off >>= 1) {
        float om = __shfl_xor(m, off, 64);
        float os = __shfl_xor(s, off, 64);
        float nm = fmaxf(m, om);
        s = s * __expf(m - nm) + os * __expf(om - nm);
        m = nm;
    }
    __shared__ float sm2[4], ss2[4];
    const int lane = threadIdx.x & 63, wid = threadIdx.x >> 6;
    if (lane == 0) { sm2[wid] = m; ss2[wid] = s; }
    __syncthreads();
    const float M = fmaxf(fmaxf(sm2[0], sm2[1]), fmaxf(sm2[2], sm2[3]));
    const float S = ss2[0]*__expf(sm2[0]-M) + ss2[1]*__expf(sm2[1]-M)
                  + ss2[2]*__expf(sm2[2]-M) + ss2[3]*__expf(sm2[3]-M);
    return make_float2(M, 1.0f / S);
}

// ---- fused cooperative version: one dispatch ----
__global__ __launch_bounds__(256) void k_fused(
        const float* __restrict__ enc, const float* __restrict__ hid,
        float* __restrict__ out, float2* __restrict__ stats) {
    phase1(enc, hid, out, stats);
    cg::this_grid().sync();                     // device-scope fence + barrier
    float2 ms = reduce_stats(stats);
    if (threadIdx.x < CHUNK / 4) {              // normalize own 32 energies (L2-local)
        const int i = blockIdx.x * CHUNK + threadIdx.x * 4;
        float4 e = *(const float4*)(out + i);
        e.x = __expf(e.x - ms.x) * ms.y;
        e.y = __expf(e.y - ms.x) * ms.y;
        e.z = __expf(e.z - ms.x) * ms.y;
        e.w = __expf(e.w - ms.x) * ms.y;
        *(float4*)(out + i) = e;
    }
}

// ---- fallback (exact R3): two kernels ----
__global__ __launch_bounds__(256) void k_matvec_stats(
        const float* __restrict__ enc, const float* __restrict__ hid,
        float* __restrict__ out, float2* __restrict__ stats) {
    phase1(enc, hid, out, stats);
}

__global__ __launch_bounds__(256) void k_softmax_scale(
        float* __restrict__ out, const float2* __restrict__ stats) {
    float2 ms = reduce_stats(stats);
    const int i = (blockIdx.x * 256 + threadIdx.x) * 4;
    float4 e = *(const float4*)(out + i);
    e.x = __expf(e.x - ms.x) * ms.y;
    e.y = __expf(e.y - ms.x) * ms.y;
    e.z = __expf(e.z - ms.x) * ms.y;
    e.w = __expf(e.w - ms.x) * ms.y;
    *(float4*)(out + i) = e;
}

extern "C" void kernel_launch(void* const* d_in, const int* in_sizes, int n_in,
                              void* d_out, int out_size, void* d_ws, size_t ws_size,
                              hipStream_t stream) {
    const float* hid = (const float*)d_in[0];   // hidden   [1024]
    const float* enc = (const float*)d_in[1];   // encoder  [65536,1024]
    float* out = (float*)d_out;                 // [65536]
    float2* stats = (float2*)d_ws;              // 2048 * 8 B = 16 KiB

    // deterministic host-side capability check (capture-safe: no stream ops)
    int maxb = 0;
    hipError_t oe = hipOccupancyMaxActiveBlocksPerMultiprocessor(&maxb, k_fused, 256, 0);
    const bool coop_ok = (oe == hipSuccess) && (maxb >= BLOCKS / 256);  // 8 blocks/CU x 256 CUs

    if (coop_ok) {
        void* args[] = { (void*)&enc, (void*)&hid, (void*)&out, (void*)&stats };
        hipLaunchCooperativeKernel((const void*)k_fused,
                                   dim3(BLOCKS), dim3(256), args, 0, stream);
    } else {
        k_matvec_stats  <<<BLOCKS, 256, 0, stream>>>(enc, hid, out, stats);
        k_softmax_scale <<<SEQ / (256 * 4), 256, 0, stream>>>(out, stats);
    }
}

// Round 7
// 48.241 us; speedup vs baseline: 3.5403x; 1.0055x over previous
//
#include <hip/hip_runtime.h>

#define SEQ 65536
#define HID 1024
#define K1_BLOCKS 2048
#define WPB 4                       // waves per block
#define NWAVES (K1_BLOCKS * WPB)    // 8192
#define RPW (SEQ / NWAVES)          // 8 rows per wave, contiguous chunk

typedef float f4 __attribute__((ext_vector_type(4)));

// K1: energies[r] = enc[r,:] . hid (one wave per row); fully-unrolled row
// loop lets the scheduler keep ~32 nontemporal f4 loads in flight.
// Per-block online-softmax stats (max, sum_exp) to ws slots (no atomics).
__global__ __launch_bounds__(256) void k_matvec_stats(
        const float* __restrict__ enc,
        const float* __restrict__ hid,
        float* __restrict__ energies,      // d_out reused as scratch
        float2* __restrict__ stats) {      // ws[0..2047]
    const int lane = threadIdx.x & 63;
    const int wid  = threadIdx.x >> 6;
    const int gw   = blockIdx.x * WPB + wid;
    const size_t base = (size_t)gw * RPW;

    // hidden hoisted into 16 regs/lane (row-invariant, L2-resident)
    const f4* __restrict__ h4 = (const f4*)hid;
    const f4 h0 = h4[lane];
    const f4 h1 = h4[lane + 64];
    const f4 h2 = h4[lane + 128];
    const f4 h3 = h4[lane + 192];

    float wmax = -INFINITY, wsum = 0.0f;
    #pragma unroll
    for (int r = 0; r < RPW; ++r) {
        const f4* __restrict__ row = (const f4*)(enc + (base + r) * HID);
        f4 a0 = __builtin_nontemporal_load(row + lane);
        f4 a1 = __builtin_nontemporal_load(row + lane + 64);
        f4 a2 = __builtin_nontemporal_load(row + lane + 128);
        f4 a3 = __builtin_nontemporal_load(row + lane + 192);
        float s = a0.x*h0.x + a0.y*h0.y + a0.z*h0.z + a0.w*h0.w
                + a1.x*h1.x + a1.y*h1.y + a1.z*h1.z + a1.w*h1.w
                + a2.x*h2.x + a2.y*h2.y + a2.z*h2.z + a2.w*h2.w
                + a3.x*h3.x + a3.y*h3.y + a3.z*h3.z + a3.w*h3.w;
        #pragma unroll
        for (int off = 32; off >= 1; off >>= 1)
            s += __shfl_xor(s, off, 64);
        if (lane == 0) energies[base + r] = s;
        // online max/sum (all lanes hold identical s)
        float nm = fmaxf(wmax, s);
        wsum = wsum * __expf(wmax - nm) + __expf(s - nm);
        wmax = nm;
    }

    __shared__ float sm[WPB], ss[WPB];
    if (lane == 0) { sm[wid] = wmax; ss[wid] = wsum; }
    __syncthreads();
    if (threadIdx.x == 0) {
        float m = fmaxf(fmaxf(sm[0], sm[1]), fmaxf(sm[2], sm[3]));
        float s = ss[0]*__expf(sm[0]-m) + ss[1]*__expf(sm[1]-m)
                + ss[2]*__expf(sm[2]-m) + ss[3]*__expf(sm[3]-m);
        stats[blockIdx.x] = make_float2(m, s);
    }
}

// K2: every block redundantly reduces the 2048 (max,sum) stats (16 KiB,
// L2-hit), then exp+normalizes ONE float4 per thread. 256 blocks so the
// kernel is ramp-dominated, not CU-count-limited.
__global__ __launch_bounds__(256) void k_softmax_scale(
        float* __restrict__ out,
        const float2* __restrict__ stats) {
    float m = -INFINITY, s = 0.0f;
    #pragma unroll
    for (int k = 0; k < K1_BLOCKS / 256; ++k) {
        float2 st = stats[k * 256 + threadIdx.x];
        float nm = fmaxf(m, st.x);
        s = s * __expf(m - nm) + st.y * __expf(st.x - nm);
        m = nm;
    }
    #pragma unroll
    for (int off = 32; off >= 1; off >>= 1) {
        float om = __shfl_xor(m, off, 64);
        float os = __shfl_xor(s, off, 64);
        float nm = fmaxf(m, om);
        s = s * __expf(m - nm) + os * __expf(om - nm);
        m = nm;
    }
    __shared__ float sm[4], ss[4];
    const int lane = threadIdx.x & 63, wid = threadIdx.x >> 6;
    if (lane == 0) { sm[wid] = m; ss[wid] = s; }
    __syncthreads();
    const float M = fmaxf(fmaxf(sm[0], sm[1]), fmaxf(sm[2], sm[3]));
    const float S = ss[0]*__expf(sm[0]-M) + ss[1]*__expf(sm[1]-M)
                  + ss[2]*__expf(sm[2]-M) + ss[3]*__expf(sm[3]-M);
    const float invS = 1.0f / S;

    const int i = (blockIdx.x * 256 + threadIdx.x) * 4;
    float4 e = *(const float4*)(out + i);
    e.x = __expf(e.x - M) * invS;
    e.y = __expf(e.y - M) * invS;
    e.z = __expf(e.z - M) * invS;
    e.w = __expf(e.w - M) * invS;
    *(float4*)(out + i) = e;
}

extern "C" void kernel_launch(void* const* d_in, const int* in_sizes, int n_in,
                              void* d_out, int out_size, void* d_ws, size_t ws_size,
                              hipStream_t stream) {
    const float* hid = (const float*)d_in[0];   // hidden   [1024]
    const float* enc = (const float*)d_in[1];   // encoder  [65536,1024]
    float* out = (float*)d_out;                 // [65536]
    float2* stats = (float2*)d_ws;              // 2048 * 8 B = 16 KiB

    k_matvec_stats  <<<K1_BLOCKS, 256, 0, stream>>>(enc, hid, out, stats);
    k_softmax_scale <<<SEQ / (256 * 4), 256, 0, stream>>>(out, stats);
}